// Round 4
// baseline (54.917 us; speedup 1.0000x reference)
//
#include <hip/hip_runtime.h>
#include <hip/hip_bf16.h>

typedef __attribute__((ext_vector_type(8))) short bf16x8;
typedef __attribute__((ext_vector_type(16))) float f32x16;

__device__ __forceinline__ unsigned short f2bf(float f) {
    unsigned u = __builtin_bit_cast(unsigned, f);
    unsigned rnd = 0x7FFFu + ((u >> 16) & 1u);
    return (unsigned short)((u + rnd) >> 16);
}

// ---------------------------------------------------------------------------
// Setup: simulate the circuit on the 256 basis vectors -> U (256x256),
// packed as bf16 B-fragments for mfma_f32_32x32x16_bf16:
//   element (n,k): v=n>>5, kt=k>>4, lane=(n&31)+32*((k>>3)&1), j=k&7
//   Bp[((v*16+kt)*64 + lane)*8 + j]
// One wave per column k; lane l holds amplitudes n = 4l + r.
// ---------------------------------------------------------------------------
__global__ __launch_bounds__(256) void qnn_setup(const float* __restrict__ wts,
                                                 unsigned short* __restrict__ Bp) {
    __shared__ float cs[56], sn[56];
    int tid = threadIdx.x;
    if (tid < 56) {
        float th = 0.5f * wts[tid];
        cs[tid] = cosf(th);
        sn[tid] = sinf(th);
    }
    __syncthreads();

    int l = tid & 63;
    int k = blockIdx.x * 4 + (tid >> 6);   // column 0..255
    int a0 = l << 2;

    float v0 = (float)(a0 + 0 == k);
    float v1 = (float)(a0 + 1 == k);
    float v2 = (float)(a0 + 2 == k);
    float v3 = (float)(a0 + 3 == k);

#pragma unroll
    for (int L = 0; L < 7; ++L) {
#pragma unroll
        for (int q = 0; q <= 5; ++q) {     // RY wires 0..5 (lane bits)
            int m = 5 - q;
            float c = cs[L * 8 + q], s = sn[L * 8 + q];
            float ss = ((l >> m) & 1) ? s : -s;
            float p0 = __shfl_xor(v0, 1 << m);
            float p1 = __shfl_xor(v1, 1 << m);
            float p2 = __shfl_xor(v2, 1 << m);
            float p3 = __shfl_xor(v3, 1 << m);
            v0 = fmaf(ss, p0, c * v0);
            v1 = fmaf(ss, p1, c * v1);
            v2 = fmaf(ss, p2, c * v2);
            v3 = fmaf(ss, p3, c * v3);
        }
        {   // RY wire 6 (reg bit 1)
            float c = cs[L * 8 + 6], s = sn[L * 8 + 6];
            float n0 = fmaf(-s, v2, c * v0), n2 = fmaf(s, v0, c * v2);
            float n1 = fmaf(-s, v3, c * v1), n3 = fmaf(s, v1, c * v3);
            v0 = n0; v1 = n1; v2 = n2; v3 = n3;
        }
        {   // RY wire 7 (reg bit 0)
            float c = cs[L * 8 + 7], s = sn[L * 8 + 7];
            float n0 = fmaf(-s, v1, c * v0), n1 = fmaf(s, v0, c * v1);
            float n2 = fmaf(-s, v3, c * v2), n3 = fmaf(s, v2, c * v3);
            v0 = n0; v1 = n1; v2 = n2; v3 = n3;
        }
        {   // CNOTs q=0..4 (both bits in lane index): composed lane permute
            int src = l;
#pragma unroll
            for (int q = 4; q >= 0; --q)
                src = src ^ (((src >> (5 - q)) & 1) << (4 - q));
            v0 = __shfl(v0, src);
            v1 = __shfl(v1, src);
            v2 = __shfl(v2, src);
            v3 = __shfl(v3, src);
        }
        {   // CNOT q=5: ctl = lane bit0, tgt = reg bit1
            bool cc = (l & 1);
            float n0 = cc ? v2 : v0, n2 = cc ? v0 : v2;
            float n1 = cc ? v3 : v1, n3 = cc ? v1 : v3;
            v0 = n0; v1 = n1; v2 = n2; v3 = n3;
        }
        {   // CNOT q=6: swap v2,v3
            float t = v2; v2 = v3; v3 = t;
        }
    }

    int kt = k >> 4, kh = (k >> 3) & 1, j = k & 7;
#pragma unroll
    for (int r = 0; r < 4; ++r) {
        int n = a0 + r;
        int v = n >> 5;
        int lane = (n & 31) + 32 * kh;
        float val = (r == 0) ? v0 : (r == 1) ? v1 : (r == 2) ? v2 : v3;
        Bp[(((v * 16 + kt) * 64) + lane) * 8 + j] = f2bf(val);
    }
}

// ---------------------------------------------------------------------------
// Main (R4): 256 blocks x 1024 thr (16 waves, 1 block/CU, single round).
// U staged once into 128 KB LDS. mfma_f32_32x32x16_bf16: wave = 32 samples
// x 128 outputs (n-half by wave parity); partial signed sums combined via
// a 2 KB LDS buffer; epilogue MLP by threads 0..255.
// ---------------------------------------------------------------------------
__global__ __launch_bounds__(1024) void qnn_main(
    const float* __restrict__ x, const unsigned short* __restrict__ Bp,
    const float* __restrict__ W1, const float* __restrict__ b1,
    const float* __restrict__ W2, const float* __restrict__ b2,
    float* __restrict__ out) {
    __shared__ __align__(16) unsigned short Blds[65536];  // 128 KB = all of U
    __shared__ float Qpart[16][32];
    __shared__ float Nrm[256];

    int tid = threadIdx.x;
    int l = tid & 63, w = tid >> 6;        // wave 0..15
    int sg = w >> 1, half = w & 1;         // sample-group, n-half
    int lr = l & 31, kh = l >> 5;          // A row-in-tile, k-half
    size_t base = (size_t)blockIdx.x * 256 * 256;

    // ---- A loads + norms + bf16 convert (issued first: deepest latency) ----
    const float* xrow = x + base + (size_t)(sg * 32 + lr) * 256 + kh * 8;
    float ss = 0.f;
    bf16x8 af[16];
#pragma unroll
    for (int kt = 0; kt < 16; ++kt) {
        float4 f0 = *(const float4*)(xrow + kt * 16);
        float4 f1 = *(const float4*)(xrow + kt * 16 + 4);
        ss = fmaf(f0.x, f0.x, fmaf(f0.y, f0.y, fmaf(f0.z, f0.z, fmaf(f0.w, f0.w, ss))));
        ss = fmaf(f1.x, f1.x, fmaf(f1.y, f1.y, fmaf(f1.z, f1.z, fmaf(f1.w, f1.w, ss))));
        bf16x8 a;
        a[0] = (short)f2bf(f0.x); a[1] = (short)f2bf(f0.y);
        a[2] = (short)f2bf(f0.z); a[3] = (short)f2bf(f0.w);
        a[4] = (short)f2bf(f1.x); a[5] = (short)f2bf(f1.y);
        a[6] = (short)f2bf(f1.z); a[7] = (short)f2bf(f1.w);
        af[kt] = a;
    }
    ss += __shfl_xor(ss, 32);              // combine the two k-halves
    if (half == 0 && l < 32) Nrm[sg * 32 + l] = ss;

    // ---- Stage B: wave w copies 8 KB, 16B/lane, wave-uniform LDS dest ----
    {
        const unsigned short* src = Bp + w * 4096 + l * 8;
        unsigned short* dst = Blds + w * 4096;
#pragma unroll
        for (int i = 0; i < 8; ++i) {
            __builtin_amdgcn_global_load_lds(
                (const __attribute__((address_space(1))) void*)(src + i * 512),
                (__attribute__((address_space(3))) void*)(dst + i * 512),
                16, 0, 0);
        }
    }

    __syncthreads();                       // B staged (vmcnt drained)

    // ---- MFMA: 4 output tiles (v) x 16 k-tiles, one acc live ----
    float q[16];
#pragma unroll
    for (int j = 0; j < 16; ++j) q[j] = 0.f;

#pragma unroll
    for (int v = 0; v < 4; ++v) {
        int vg = half * 4 + v;
        const unsigned short* bl = Blds + vg * 8192 + l * 8;
        f32x16 acc;
#pragma unroll
        for (int j = 0; j < 16; ++j) acc[j] = 0.f;
#pragma unroll
        for (int kt = 0; kt < 16; ++kt) {
            bf16x8 bf = *(const bf16x8*)(bl + kt * 512);
            acc = __builtin_amdgcn_mfma_f32_32x32x16_bf16(af[kt], bf, acc, 0, 0, 0);
        }
#pragma unroll
        for (int j = 0; j < 16; ++j) q[j] = fmaf(acc[j], acc[j], q[j]);
    }

    // reduce over the 32 output-columns held across lanes (within k-half)
#pragma unroll
    for (int d = 1; d < 32; d <<= 1) {
#pragma unroll
        for (int j = 0; j < 16; ++j) q[j] += __shfl_xor(q[j], d);
    }
    // C/D rows: row = (j&3) + 8*(j>>2) + 4*kh  (m74/m101)
    if ((l & 31) == 0) {
#pragma unroll
        for (int j = 0; j < 16; ++j)
            Qpart[w][(j & 3) + 8 * (j >> 2) + 4 * kh] = q[j];
    }

    __syncthreads();

    // ---- Epilogue: one thread per sample ----
    if (tid < 256) {
        int s = tid, g = s >> 5, rl = s & 31;
        float z = (Qpart[2 * g][rl] - Qpart[2 * g + 1][rl]) / Nrm[s];
        float o = b2[0];
#pragma unroll
        for (int jj = 0; jj < 16; ++jj) {
            float h = fmaf(z, W1[jj], b1[jj]);
            h = h > 0.f ? h : 0.f;
            o = fmaf(W2[jj], h, o);
        }
        out[(size_t)blockIdx.x * 256 + s] = 1.f / (1.f + expf(-o));
    }
}

extern "C" void kernel_launch(void* const* d_in, const int* in_sizes, int n_in,
                              void* d_out, int out_size, void* d_ws, size_t ws_size,
                              hipStream_t stream) {
    const float* x   = (const float*)d_in[0];
    const float* wts = (const float*)d_in[1];
    const float* W1  = (const float*)d_in[2];
    const float* b1  = (const float*)d_in[3];
    const float* W2  = (const float*)d_in[4];
    const float* b2  = (const float*)d_in[5];
    float* out = (float*)d_out;
    unsigned short* Bp = (unsigned short*)d_ws;   // 65536 bf16 = 128 KB

    int B = in_sizes[0] >> 8;        // 65536 samples
    qnn_setup<<<64, 256, 0, stream>>>(wts, Bp);
    qnn_main<<<B / 256, 1024, 0, stream>>>(x, Bp, W1, b1, W2, b2, out);
}

// Round 5
// 29.974 us; speedup vs baseline: 1.8322x; 1.8322x over previous
//
#include <hip/hip_runtime.h>
#include <hip/hip_bf16.h>

typedef __attribute__((ext_vector_type(8))) short bf16x8;
typedef __attribute__((ext_vector_type(4))) float f32x4;

__device__ __forceinline__ unsigned short f2bf(float f) {
    unsigned u = __builtin_bit_cast(unsigned, f);
    unsigned rnd = 0x7FFFu + ((u >> 16) & 1u);
    return (unsigned short)((u + rnd) >> 16);
}

// ---------------------------------------------------------------------------
// Setup: simulate the circuit on the 256 basis vectors -> U (256x256),
// packed as bf16 B-fragments for mfma_f32_16x16x32_bf16 (R3-proven layout):
//   element (n,k): u=n>>4, t=k>>5, lane=((k>>3)&3)*16+(n&15), j=k&7
//   Bp[((u*8+t)*64 + lane)*8 + j]
// ---------------------------------------------------------------------------
__global__ __launch_bounds__(256) void qnn_setup(const float* __restrict__ wts,
                                                 unsigned short* __restrict__ Bp) {
    __shared__ float cs[56], sn[56];
    int tid = threadIdx.x;
    if (tid < 56) {
        float th = 0.5f * wts[tid];
        cs[tid] = cosf(th);
        sn[tid] = sinf(th);
    }
    __syncthreads();

    int l = tid & 63;
    int k = blockIdx.x * 4 + (tid >> 6);   // column 0..255
    int a0 = l << 2;

    float v0 = (float)(a0 + 0 == k);
    float v1 = (float)(a0 + 1 == k);
    float v2 = (float)(a0 + 2 == k);
    float v3 = (float)(a0 + 3 == k);

#pragma unroll
    for (int L = 0; L < 7; ++L) {
#pragma unroll
        for (int q = 0; q <= 5; ++q) {     // RY wires 0..5 (lane bits)
            int m = 5 - q;
            float c = cs[L * 8 + q], s = sn[L * 8 + q];
            float ss = ((l >> m) & 1) ? s : -s;
            float p0 = __shfl_xor(v0, 1 << m);
            float p1 = __shfl_xor(v1, 1 << m);
            float p2 = __shfl_xor(v2, 1 << m);
            float p3 = __shfl_xor(v3, 1 << m);
            v0 = fmaf(ss, p0, c * v0);
            v1 = fmaf(ss, p1, c * v1);
            v2 = fmaf(ss, p2, c * v2);
            v3 = fmaf(ss, p3, c * v3);
        }
        {   // RY wire 6 (reg bit 1)
            float c = cs[L * 8 + 6], s = sn[L * 8 + 6];
            float n0 = fmaf(-s, v2, c * v0), n2 = fmaf(s, v0, c * v2);
            float n1 = fmaf(-s, v3, c * v1), n3 = fmaf(s, v1, c * v3);
            v0 = n0; v1 = n1; v2 = n2; v3 = n3;
        }
        {   // RY wire 7 (reg bit 0)
            float c = cs[L * 8 + 7], s = sn[L * 8 + 7];
            float n0 = fmaf(-s, v1, c * v0), n1 = fmaf(s, v0, c * v1);
            float n2 = fmaf(-s, v3, c * v2), n3 = fmaf(s, v2, c * v3);
            v0 = n0; v1 = n1; v2 = n2; v3 = n3;
        }
        {   // CNOTs q=0..4 (both bits in lane index): composed lane permute
            int src = l;
#pragma unroll
            for (int q = 4; q >= 0; --q)
                src = src ^ (((src >> (5 - q)) & 1) << (4 - q));
            v0 = __shfl(v0, src);
            v1 = __shfl(v1, src);
            v2 = __shfl(v2, src);
            v3 = __shfl(v3, src);
        }
        {   // CNOT q=5: ctl = lane bit0, tgt = reg bit1
            bool cc = (l & 1);
            float n0 = cc ? v2 : v0, n2 = cc ? v0 : v2;
            float n1 = cc ? v3 : v1, n3 = cc ? v1 : v3;
            v0 = n0; v1 = n1; v2 = n2; v3 = n3;
        }
        {   // CNOT q=6: swap v2,v3
            float t = v2; v2 = v3; v3 = t;
        }
    }

    int t = k >> 5, j = k & 7, lk = (k >> 3) & 3;
#pragma unroll
    for (int r = 0; r < 4; ++r) {
        int n = a0 + r;
        int u = n >> 4;
        int ls = lk * 16 + (n & 15);
        float val = (r == 0) ? v0 : (r == 1) ? v1 : (r == 2) ? v2 : v3;
        Bp[(((u * 8 + t) * 64) + ls) * 8 + j] = f2bf(val);
    }
}

// ---------------------------------------------------------------------------
// Main (R5): 256 blocks x 512 thr, 1 block/CU, SINGLE round. U staged once
// into 128 KB LDS via global_load_lds. Each wave owns 32 samples (two
// 16-row A-tiles) so every B-fragment ds_read feeds 4 MFMAs -> B LDS
// traffic halved vs R3. No spill: launch_bounds(512,2) = 256-VGPR cap.
// ---------------------------------------------------------------------------
__global__ __launch_bounds__(512, 2) void qnn_main(
    const float* __restrict__ x, const unsigned short* __restrict__ Bp,
    const float* __restrict__ W1, const float* __restrict__ b1,
    const float* __restrict__ W2, const float* __restrict__ b2,
    float* __restrict__ out) {
    __shared__ __align__(16) unsigned short Blds[65536];   // 128 KB = all of U

    int tid = threadIdx.x;
    int l = tid & 63, w = tid >> 6;
    size_t base = (size_t)blockIdx.x * 256 * 256;          // 256 samples/block

    // ---- Stage B first (oldest in the vmem queue, drains at the barrier) ----
    {
        const unsigned short* src = Bp + w * 8192 + l * 8;
        unsigned short* dst = Blds + w * 8192;             // wave-uniform base
#pragma unroll
        for (int i = 0; i < 16; ++i) {
            __builtin_amdgcn_global_load_lds(
                (const __attribute__((address_space(1))) void*)(src + i * 512),
                (__attribute__((address_space(3))) void*)(dst + i * 512),
                16, 0, 0);
        }
    }

    // ---- A-fragments direct from global. Wave w: samples 32w..32w+31.
    // Lane l: row-in-tile = l&15, k-group kg = l>>4 covers k = 32t+8kg..+7.
    const float* xr0 = x + base + (size_t)(32 * w + (l & 15)) * 256 + (l >> 4) * 8;
    const float* xr1 = xr0 + 16 * 256;

    bf16x8 af0[8], af1[8];
    float ss0 = 0.f, ss1 = 0.f;
    {
        float4 fa[16];
#pragma unroll
        for (int t = 0; t < 8; ++t) {
            fa[2 * t]     = *(const float4*)(xr0 + t * 32);
            fa[2 * t + 1] = *(const float4*)(xr0 + t * 32 + 4);
        }
#pragma unroll
        for (int t = 0; t < 8; ++t) {
            float4 f0 = fa[2 * t], f1 = fa[2 * t + 1];
            ss0 = fmaf(f0.x, f0.x, fmaf(f0.y, f0.y, fmaf(f0.z, f0.z, fmaf(f0.w, f0.w, ss0))));
            ss0 = fmaf(f1.x, f1.x, fmaf(f1.y, f1.y, fmaf(f1.z, f1.z, fmaf(f1.w, f1.w, ss0))));
            bf16x8 a;
            a[0] = (short)f2bf(f0.x); a[1] = (short)f2bf(f0.y);
            a[2] = (short)f2bf(f0.z); a[3] = (short)f2bf(f0.w);
            a[4] = (short)f2bf(f1.x); a[5] = (short)f2bf(f1.y);
            a[6] = (short)f2bf(f1.z); a[7] = (short)f2bf(f1.w);
            af0[t] = a;
        }
    }
    {
        float4 fa[16];
#pragma unroll
        for (int t = 0; t < 8; ++t) {
            fa[2 * t]     = *(const float4*)(xr1 + t * 32);
            fa[2 * t + 1] = *(const float4*)(xr1 + t * 32 + 4);
        }
#pragma unroll
        for (int t = 0; t < 8; ++t) {
            float4 f0 = fa[2 * t], f1 = fa[2 * t + 1];
            ss1 = fmaf(f0.x, f0.x, fmaf(f0.y, f0.y, fmaf(f0.z, f0.z, fmaf(f0.w, f0.w, ss1))));
            ss1 = fmaf(f1.x, f1.x, fmaf(f1.y, f1.y, fmaf(f1.z, f1.z, fmaf(f1.w, f1.w, ss1))));
            bf16x8 a;
            a[0] = (short)f2bf(f0.x); a[1] = (short)f2bf(f0.y);
            a[2] = (short)f2bf(f0.z); a[3] = (short)f2bf(f0.w);
            a[4] = (short)f2bf(f1.x); a[5] = (short)f2bf(f1.y);
            a[6] = (short)f2bf(f1.z); a[7] = (short)f2bf(f1.w);
            af1[t] = a;
        }
    }
    // row norms: combine the 4 k-groups (lane bits 4,5)
    ss0 += __shfl_xor(ss0, 16); ss0 += __shfl_xor(ss0, 32);
    ss1 += __shfl_xor(ss1, 16); ss1 += __shfl_xor(ss1, 32);

    __syncthreads();                   // B staged (barrier drains vmcnt)

    // ---- u-pair-outer MFMA: 4 acc chains, each B-frag read feeds 4 MFMAs ----
    float q0[4] = {0.f, 0.f, 0.f, 0.f};
    float q1[4] = {0.f, 0.f, 0.f, 0.f};
    const unsigned short* bl = &Blds[l * 8];
#pragma unroll
    for (int u = 0; u < 16; u += 2) {
        f32x4 a00 = {0.f, 0.f, 0.f, 0.f}, a01 = {0.f, 0.f, 0.f, 0.f};
        f32x4 a10 = {0.f, 0.f, 0.f, 0.f}, a11 = {0.f, 0.f, 0.f, 0.f};
#pragma unroll
        for (int t = 0; t < 8; ++t) {
            bf16x8 b0 = *(const bf16x8*)(bl + ((u    ) * 8 + t) * 512);
            bf16x8 b1 = *(const bf16x8*)(bl + ((u + 1) * 8 + t) * 512);
            a00 = __builtin_amdgcn_mfma_f32_16x16x32_bf16(af0[t], b0, a00, 0, 0, 0);
            a10 = __builtin_amdgcn_mfma_f32_16x16x32_bf16(af1[t], b0, a10, 0, 0, 0);
            a01 = __builtin_amdgcn_mfma_f32_16x16x32_bf16(af0[t], b1, a01, 0, 0, 0);
            a11 = __builtin_amdgcn_mfma_f32_16x16x32_bf16(af1[t], b1, a11, 0, 0, 0);
        }
        float sgn = (u < 8) ? 1.f : -1.f;   // n < 128 <=> u < 8
#pragma unroll
        for (int j = 0; j < 4; ++j) {
            q0[j] = fmaf(sgn * a00[j], a00[j], q0[j]);
            q0[j] = fmaf(sgn * a01[j], a01[j], q0[j]);
            q1[j] = fmaf(sgn * a10[j], a10[j], q1[j]);
            q1[j] = fmaf(sgn * a11[j], a11[j], q1[j]);
        }
    }
#pragma unroll
    for (int d = 1; d < 16; d <<= 1) {
#pragma unroll
        for (int j = 0; j < 4; ++j) {
            q0[j] += __shfl_xor(q0[j], d);
            q1[j] += __shfl_xor(q1[j], d);
        }
    }

    // norm for the rows this lane writes (C/D: row=(l>>4)*4+j, col=l&15)
    float nrm0 = __shfl(ss0, ((l >> 4) << 2) | (l & 3));
    float nrm1 = __shfl(ss1, ((l >> 4) << 2) | (l & 3));

    if ((l & 15) < 4) {
        int j = l & 3;
        int r0 = 32 * w + (l >> 4) * 4 + j;          // tile0 sample
        float qv0 = (j == 0) ? q0[0] : (j == 1) ? q0[1] : (j == 2) ? q0[2] : q0[3];
        float qv1 = (j == 0) ? q1[0] : (j == 1) ? q1[1] : (j == 2) ? q1[2] : q1[3];
        float z0 = qv0 / nrm0;
        float z1 = qv1 / nrm1;
        float o0 = b2[0], o1 = b2[0];
#pragma unroll
        for (int jj = 0; jj < 16; ++jj) {
            float w1v = W1[jj], b1v = b1[jj], w2v = W2[jj];
            float h0 = fmaf(z0, w1v, b1v); h0 = h0 > 0.f ? h0 : 0.f;
            float h1 = fmaf(z1, w1v, b1v); h1 = h1 > 0.f ? h1 : 0.f;
            o0 = fmaf(w2v, h0, o0);
            o1 = fmaf(w2v, h1, o1);
        }
        size_t ob = (size_t)blockIdx.x * 256;
        out[ob + r0]      = 1.f / (1.f + expf(-o0));
        out[ob + r0 + 16] = 1.f / (1.f + expf(-o1));
    }
}

extern "C" void kernel_launch(void* const* d_in, const int* in_sizes, int n_in,
                              void* d_out, int out_size, void* d_ws, size_t ws_size,
                              hipStream_t stream) {
    const float* x   = (const float*)d_in[0];
    const float* wts = (const float*)d_in[1];
    const float* W1  = (const float*)d_in[2];
    const float* b1  = (const float*)d_in[3];
    const float* W2  = (const float*)d_in[4];
    const float* b2  = (const float*)d_in[5];
    float* out = (float*)d_out;
    unsigned short* Bp = (unsigned short*)d_ws;   // 65536 bf16 = 128 KB

    int B = in_sizes[0] >> 8;        // 65536 samples
    qnn_setup<<<64, 256, 0, stream>>>(wts, Bp);
    qnn_main<<<B / 256, 512, 0, stream>>>(x, Bp, W1, b1, W2, b2, out);
}

// Round 6
// 29.695 us; speedup vs baseline: 1.8493x; 1.0094x over previous
//
#include <hip/hip_runtime.h>
#include <hip/hip_bf16.h>

typedef __attribute__((ext_vector_type(8))) short bf16x8;
typedef __attribute__((ext_vector_type(4))) float f32x4;

__device__ __forceinline__ unsigned short f2bf(float f) {
    unsigned u = __builtin_bit_cast(unsigned, f);
    unsigned rnd = 0x7FFFu + ((u >> 16) & 1u);
    return (unsigned short)((u + rnd) >> 16);
}

// ---------------------------------------------------------------------------
// Setup: simulate the circuit on the 256 basis vectors -> U (256x256),
// packed as bf16 B-fragments for mfma_f32_16x16x32_bf16 (proven layout):
//   element (n,k): u=n>>4, t=k>>5, lane=((k>>3)&3)*16+(n&15), j=k&7
//   Bp[((u*8+t)*64 + lane)*8 + j]
// ---------------------------------------------------------------------------
__global__ __launch_bounds__(256) void qnn_setup(const float* __restrict__ wts,
                                                 unsigned short* __restrict__ Bp) {
    __shared__ float cs[56], sn[56];
    int tid = threadIdx.x;
    if (tid < 56) {
        float th = 0.5f * wts[tid];
        cs[tid] = cosf(th);
        sn[tid] = sinf(th);
    }
    __syncthreads();

    int l = tid & 63;
    int k = blockIdx.x * 4 + (tid >> 6);   // column 0..255
    int a0 = l << 2;

    float v0 = (float)(a0 + 0 == k);
    float v1 = (float)(a0 + 1 == k);
    float v2 = (float)(a0 + 2 == k);
    float v3 = (float)(a0 + 3 == k);

#pragma unroll
    for (int L = 0; L < 7; ++L) {
#pragma unroll
        for (int q = 0; q <= 5; ++q) {     // RY wires 0..5 (lane bits)
            int m = 5 - q;
            float c = cs[L * 8 + q], s = sn[L * 8 + q];
            float ss = ((l >> m) & 1) ? s : -s;
            float p0 = __shfl_xor(v0, 1 << m);
            float p1 = __shfl_xor(v1, 1 << m);
            float p2 = __shfl_xor(v2, 1 << m);
            float p3 = __shfl_xor(v3, 1 << m);
            v0 = fmaf(ss, p0, c * v0);
            v1 = fmaf(ss, p1, c * v1);
            v2 = fmaf(ss, p2, c * v2);
            v3 = fmaf(ss, p3, c * v3);
        }
        {   // RY wire 6 (reg bit 1)
            float c = cs[L * 8 + 6], s = sn[L * 8 + 6];
            float n0 = fmaf(-s, v2, c * v0), n2 = fmaf(s, v0, c * v2);
            float n1 = fmaf(-s, v3, c * v1), n3 = fmaf(s, v1, c * v3);
            v0 = n0; v1 = n1; v2 = n2; v3 = n3;
        }
        {   // RY wire 7 (reg bit 0)
            float c = cs[L * 8 + 7], s = sn[L * 8 + 7];
            float n0 = fmaf(-s, v1, c * v0), n1 = fmaf(s, v0, c * v1);
            float n2 = fmaf(-s, v3, c * v2), n3 = fmaf(s, v2, c * v3);
            v0 = n0; v1 = n1; v2 = n2; v3 = n3;
        }
        {   // CNOTs q=0..4 (both bits in lane index): composed lane permute
            int src = l;
#pragma unroll
            for (int q = 4; q >= 0; --q)
                src = src ^ (((src >> (5 - q)) & 1) << (4 - q));
            v0 = __shfl(v0, src);
            v1 = __shfl(v1, src);
            v2 = __shfl(v2, src);
            v3 = __shfl(v3, src);
        }
        {   // CNOT q=5: ctl = lane bit0, tgt = reg bit1
            bool cc = (l & 1);
            float n0 = cc ? v2 : v0, n2 = cc ? v0 : v2;
            float n1 = cc ? v3 : v1, n3 = cc ? v1 : v3;
            v0 = n0; v1 = n1; v2 = n2; v3 = n3;
        }
        {   // CNOT q=6: swap v2,v3
            float t = v2; v2 = v3; v3 = t;
        }
    }

    int t = k >> 5, j = k & 7, lk = (k >> 3) & 3;
#pragma unroll
    for (int r = 0; r < 4; ++r) {
        int n = a0 + r;
        int u = n >> 4;
        int ls = lk * 16 + (n & 15);
        float val = (r == 0) ? v0 : (r == 1) ? v1 : (r == 2) ? v2 : v3;
        Bp[(((u * 8 + t) * 64) + ls) * 8 + j] = f2bf(val);
    }
}

// stage one 32 KB quarter of U (u-blocks 4q..4q+3); wave w copies 8 KB
__device__ __forceinline__ void stage_qtr(const unsigned short* __restrict__ Bp,
                                          unsigned short* buf, int qtr, int w, int l) {
    const unsigned short* src = Bp + qtr * 16384 + w * 4096 + l * 8;
    unsigned short* dst = buf + w * 4096;
#pragma unroll
    for (int i = 0; i < 8; ++i) {
        __builtin_amdgcn_global_load_lds(
            (const __attribute__((address_space(1))) void*)(src + i * 512),
            (__attribute__((address_space(3))) void*)(dst + i * 512),
            16, 0, 0);
    }
}

// compute one quarter (4 u-blocks) for this wave's two 16-row tiles
__device__ __forceinline__ void compute_qtr(const unsigned short* buf, int l,
                                            const bf16x8* af0, const bf16x8* af1,
                                            float sgn, float* q0, float* q1) {
    const unsigned short* bl = buf + l * 8;
#pragma unroll
    for (int up = 0; up < 2; ++up) {
        f32x4 a00 = {0.f, 0.f, 0.f, 0.f}, a01 = {0.f, 0.f, 0.f, 0.f};
        f32x4 a10 = {0.f, 0.f, 0.f, 0.f}, a11 = {0.f, 0.f, 0.f, 0.f};
#pragma unroll
        for (int t = 0; t < 8; ++t) {
            bf16x8 b0 = *(const bf16x8*)(bl + ((up * 2    ) * 8 + t) * 512);
            bf16x8 b1 = *(const bf16x8*)(bl + ((up * 2 + 1) * 8 + t) * 512);
            a00 = __builtin_amdgcn_mfma_f32_16x16x32_bf16(af0[t], b0, a00, 0, 0, 0);
            a10 = __builtin_amdgcn_mfma_f32_16x16x32_bf16(af1[t], b0, a10, 0, 0, 0);
            a01 = __builtin_amdgcn_mfma_f32_16x16x32_bf16(af0[t], b1, a01, 0, 0, 0);
            a11 = __builtin_amdgcn_mfma_f32_16x16x32_bf16(af1[t], b1, a11, 0, 0, 0);
        }
#pragma unroll
        for (int j = 0; j < 4; ++j) {
            q0[j] = fmaf(sgn * a00[j], a00[j], q0[j]);
            q0[j] = fmaf(sgn * a01[j], a01[j], q0[j]);
            q1[j] = fmaf(sgn * a10[j], a10[j], q1[j]);
            q1[j] = fmaf(sgn * a11[j], a11[j], q1[j]);
        }
    }
}

// ---------------------------------------------------------------------------
// Main (R6): 512 blocks x 256 thr (4 waves), 64 KB LDS -> 2 blocks/CU.
// U split into four 32 KB quarters ping-ponged through BufA/BufB:
// stage[q+1] issued BEFORE compute[q] so the barrier's vmcnt drain is free;
// the co-resident second block fills remaining gaps. 32 samples/wave.
// ---------------------------------------------------------------------------
__global__ __launch_bounds__(256, 2) void qnn_main(
    const float* __restrict__ x, const unsigned short* __restrict__ Bp,
    const float* __restrict__ W1, const float* __restrict__ b1,
    const float* __restrict__ W2, const float* __restrict__ b2,
    float* __restrict__ out) {
    __shared__ __align__(16) unsigned short BufA[16384];   // 32 KB
    __shared__ __align__(16) unsigned short BufB[16384];   // 32 KB

    int tid = threadIdx.x;
    int l = tid & 63, w = tid >> 6;                        // wave 0..3
    size_t base = (size_t)blockIdx.x * 128 * 256;          // 128 samples/block

    // ---- A-fragment loads first (deepest latency), then stage quarter 0 ----
    const float* xr0 = x + base + (size_t)(32 * w + (l & 15)) * 256 + (l >> 4) * 8;
    const float* xr1 = xr0 + 16 * 256;
    float4 fa0[16], fa1[16];
#pragma unroll
    for (int t = 0; t < 8; ++t) {
        fa0[2 * t]     = *(const float4*)(xr0 + t * 32);
        fa0[2 * t + 1] = *(const float4*)(xr0 + t * 32 + 4);
    }
#pragma unroll
    for (int t = 0; t < 8; ++t) {
        fa1[2 * t]     = *(const float4*)(xr1 + t * 32);
        fa1[2 * t + 1] = *(const float4*)(xr1 + t * 32 + 4);
    }
    stage_qtr(Bp, BufA, 0, w, l);

    // ---- convert + norms (waits on A loads; quarter-0 stage stays in flight) ----
    bf16x8 af0[8], af1[8];
    float ss0 = 0.f, ss1 = 0.f;
#pragma unroll
    for (int t = 0; t < 8; ++t) {
        float4 f0 = fa0[2 * t], f1 = fa0[2 * t + 1];
        ss0 = fmaf(f0.x, f0.x, fmaf(f0.y, f0.y, fmaf(f0.z, f0.z, fmaf(f0.w, f0.w, ss0))));
        ss0 = fmaf(f1.x, f1.x, fmaf(f1.y, f1.y, fmaf(f1.z, f1.z, fmaf(f1.w, f1.w, ss0))));
        bf16x8 a;
        a[0] = (short)f2bf(f0.x); a[1] = (short)f2bf(f0.y);
        a[2] = (short)f2bf(f0.z); a[3] = (short)f2bf(f0.w);
        a[4] = (short)f2bf(f1.x); a[5] = (short)f2bf(f1.y);
        a[6] = (short)f2bf(f1.z); a[7] = (short)f2bf(f1.w);
        af0[t] = a;
    }
#pragma unroll
    for (int t = 0; t < 8; ++t) {
        float4 f0 = fa1[2 * t], f1 = fa1[2 * t + 1];
        ss1 = fmaf(f0.x, f0.x, fmaf(f0.y, f0.y, fmaf(f0.z, f0.z, fmaf(f0.w, f0.w, ss1))));
        ss1 = fmaf(f1.x, f1.x, fmaf(f1.y, f1.y, fmaf(f1.z, f1.z, fmaf(f1.w, f1.w, ss1))));
        bf16x8 a;
        a[0] = (short)f2bf(f0.x); a[1] = (short)f2bf(f0.y);
        a[2] = (short)f2bf(f0.z); a[3] = (short)f2bf(f0.w);
        a[4] = (short)f2bf(f1.x); a[5] = (short)f2bf(f1.y);
        a[6] = (short)f2bf(f1.z); a[7] = (short)f2bf(f1.w);
        af1[t] = a;
    }
    ss0 += __shfl_xor(ss0, 16); ss0 += __shfl_xor(ss0, 32);
    ss1 += __shfl_xor(ss1, 16); ss1 += __shfl_xor(ss1, 32);

    float q0[4] = {0.f, 0.f, 0.f, 0.f};
    float q1[4] = {0.f, 0.f, 0.f, 0.f};

    __syncthreads();                                  // quarter 0 staged
    stage_qtr(Bp, BufB, 1, w, l);                     // issue next stage first
    compute_qtr(BufA, l, af0, af1,  1.f, q0, q1);     // u 0..3  (n<128: +)
    __syncthreads();
    stage_qtr(Bp, BufA, 2, w, l);
    compute_qtr(BufB, l, af0, af1,  1.f, q0, q1);     // u 4..7  (+)
    __syncthreads();
    stage_qtr(Bp, BufB, 3, w, l);
    compute_qtr(BufA, l, af0, af1, -1.f, q0, q1);     // u 8..11 (−)
    __syncthreads();
    compute_qtr(BufB, l, af0, af1, -1.f, q0, q1);     // u 12..15 (−)

    // ---- reduce across the 16 output-columns, then MLP epilogue ----
#pragma unroll
    for (int d = 1; d < 16; d <<= 1) {
#pragma unroll
        for (int j = 0; j < 4; ++j) {
            q0[j] += __shfl_xor(q0[j], d);
            q1[j] += __shfl_xor(q1[j], d);
        }
    }

    // norm for the rows this lane writes (C/D: row=(l>>4)*4+j, col=l&15)
    float nrm0 = __shfl(ss0, ((l >> 4) << 2) | (l & 3));
    float nrm1 = __shfl(ss1, ((l >> 4) << 2) | (l & 3));

    if ((l & 15) < 4) {
        int j = l & 3;
        int r0 = 32 * w + (l >> 4) * 4 + j;
        float qv0 = (j == 0) ? q0[0] : (j == 1) ? q0[1] : (j == 2) ? q0[2] : q0[3];
        float qv1 = (j == 0) ? q1[0] : (j == 1) ? q1[1] : (j == 2) ? q1[2] : q1[3];
        float z0 = qv0 / nrm0;
        float z1 = qv1 / nrm1;
        float o0 = b2[0], o1 = b2[0];
#pragma unroll
        for (int jj = 0; jj < 16; ++jj) {
            float w1v = W1[jj], b1v = b1[jj], w2v = W2[jj];
            float h0 = fmaf(z0, w1v, b1v); h0 = h0 > 0.f ? h0 : 0.f;
            float h1 = fmaf(z1, w1v, b1v); h1 = h1 > 0.f ? h1 : 0.f;
            o0 = fmaf(w2v, h0, o0);
            o1 = fmaf(w2v, h1, o1);
        }
        size_t ob = (size_t)blockIdx.x * 128;
        out[ob + r0]      = 1.f / (1.f + expf(-o0));
        out[ob + r0 + 16] = 1.f / (1.f + expf(-o1));
    }
}

extern "C" void kernel_launch(void* const* d_in, const int* in_sizes, int n_in,
                              void* d_out, int out_size, void* d_ws, size_t ws_size,
                              hipStream_t stream) {
    const float* x   = (const float*)d_in[0];
    const float* wts = (const float*)d_in[1];
    const float* W1  = (const float*)d_in[2];
    const float* b1  = (const float*)d_in[3];
    const float* W2  = (const float*)d_in[4];
    const float* b2  = (const float*)d_in[5];
    float* out = (float*)d_out;
    unsigned short* Bp = (unsigned short*)d_ws;   // 65536 bf16 = 128 KB

    int B = in_sizes[0] >> 8;        // 65536 samples
    qnn_setup<<<64, 256, 0, stream>>>(wts, Bp);
    qnn_main<<<B / 128, 256, 0, stream>>>(x, Bp, W1, b1, W2, b2, out);
}